// Round 4
// baseline (304.783 us; speedup 1.0000x reference)
//
#include <hip/hip_runtime.h>
#include <math.h>

#define Bp 32
#define Vp 48
#define Ip 24
#define Hp 768
#define EPS 1e-5f

#define EFFECTS_SIZE (Bp*Ip*Vp*Hp)   // 28,311,552
#define GRAPH_SIZE   (Bp*Vp*Vp)      // 73,728
#define ENC_SIZE     (Bp*Vp*Hp)      // 1,179,648
#define MS           (Hp*Hp)         // packed matrix size in ushorts

typedef __attribute__((ext_vector_type(8))) short short8;
typedef __attribute__((ext_vector_type(4))) float floatx4;
typedef __attribute__((ext_vector_type(2))) float floatx2;
typedef __attribute__((ext_vector_type(4))) unsigned int uintx4;

__device__ __forceinline__ unsigned short f2bf(float f) {
    unsigned int u = __float_as_uint(f);
    u += 0x7fffu + ((u >> 16) & 1u);
    return (unsigned short)(u >> 16);
}
__device__ __forceinline__ unsigned int f2bf2(float a, float b) {
    return (unsigned int)f2bf(a) | ((unsigned int)f2bf(b) << 16);
}

// LN+ReLU 8 consecutive elements (two floatx4) -> packed bf16x8
__device__ __forceinline__ uintx4 ln8(floatx4 xa, floatx4 xb, float mu, float rs,
                                      floatx4 ga, floatx4 gb, floatx4 ba, floatx4 bb)
{
    float y0 = fmaxf((xa.x - mu) * rs * ga.x + ba.x, 0.f);
    float y1 = fmaxf((xa.y - mu) * rs * ga.y + ba.y, 0.f);
    float y2 = fmaxf((xa.z - mu) * rs * ga.z + ba.z, 0.f);
    float y3 = fmaxf((xa.w - mu) * rs * ga.w + ba.w, 0.f);
    float y4 = fmaxf((xb.x - mu) * rs * gb.x + bb.x, 0.f);
    float y5 = fmaxf((xb.y - mu) * rs * gb.y + bb.y, 0.f);
    float y6 = fmaxf((xb.z - mu) * rs * gb.z + bb.z, 0.f);
    float y7 = fmaxf((xb.w - mu) * rs * gb.w + bb.w, 0.f);
    uintx4 v;
    v.x = f2bf2(y0, y1); v.y = f2bf2(y2, y3);
    v.z = f2bf2(y4, y5); v.w = f2bf2(y6, y7);
    return v;
}

// ---------------------------------------------------------------------------
// Pack 6 H x H weight blocks into MFMA B-operand layout (bf16).
// packed[m][((T*24+kb)*64+lane)*8 + j] = W[kb*32+(lane>>4)*8+j][T*16+(lane&15)]
// slots: 0=W_enc 1=Wg1a 2=Wg1b 3=Wi1b 4=Wi1a 5=Wi2
// ---------------------------------------------------------------------------
__global__ __launch_bounds__(256) void pack_weights(
    const float* __restrict__ W_enc, const float* __restrict__ Wg1,
    const float* __restrict__ Wi1, const float* __restrict__ Wi2,
    unsigned short* __restrict__ packed)
{
    const int bid = blockIdx.x;          // 0..1727
    const int m = bid / 288;
    const int rem = bid - m * 288;
    const int T = rem / 6;
    const int u = rem - T * 6;
    const float* src;
    switch (m) {
        case 0: src = W_enc; break;
        case 1: src = Wg1; break;
        case 2: src = Wg1 + Hp * Hp; break;
        case 3: src = Wi1 + Hp * Hp; break;
        case 4: src = Wi1; break;
        default: src = Wi2; break;
    }
    unsigned short* dst = packed + (size_t)m * MS;
    const int lane = threadIdx.x & 63;
    const int kq = threadIdx.x >> 6;     // 0..3
    const int col = T * 16 + (lane & 15);
    const int krow0 = (lane >> 4) * 8;
    const int kb = kq + 4 * u;           // 0..23
    unsigned int w[4];
#pragma unroll
    for (int p2 = 0; p2 < 4; ++p2) {
        float f0 = src[(size_t)(kb * 32 + krow0 + 2 * p2)     * Hp + col];
        float f1 = src[(size_t)(kb * 32 + krow0 + 2 * p2 + 1) * Hp + col];
        w[p2] = f2bf2(f0, f1);
    }
    uintx4 v; v.x = w[0]; v.y = w[1]; v.z = w[2]; v.w = w[3];
    *(uintx4*)(dst + ((size_t)(T * 24 + kb) * 64 + lane) * 8) = v;
}

// ---------------------------------------------------------------------------
// Convert variables+interventions fp32 -> bf16; block 0 also builds bias2304.
// ---------------------------------------------------------------------------
__global__ __launch_bounds__(256) void convert_inputs(
    const float* __restrict__ vars, const float* __restrict__ intv,
    const float* __restrict__ bg1, const float* __restrict__ bi1,
    unsigned short* __restrict__ varb, unsigned short* __restrict__ intvb,
    float* __restrict__ bias2304)
{
    const int p = blockIdx.x * 256 + threadIdx.x;
    const int VPn = ENC_SIZE / 2;
    if (p < VPn) {
        float2 f = ((const float2*)vars)[p];
        ((unsigned int*)varb)[p] = f2bf2(f.x, f.y);
    } else {
        int q = p - VPn;
        float2 f = ((const float2*)intv)[q];
        ((unsigned int*)intvb)[q] = f2bf2(f.x, f.y);
    }
    if (blockIdx.x == 0) {
        for (int t = threadIdx.x; t < 2304; t += 256)
            bias2304[t] = (t < 768) ? 0.0f : (t < 1536 ? bg1[t - 768] : bi1[t - 1536]);
    }
}

// ---------------------------------------------------------------------------
// gemm32: C[M x N] = A_bf16[M x 768] @ Bpacked (+bias).
// Block = 32 rows x 192 cols (grid.x = M/32, grid.y = N/192). 48 KB LDS.
// Wave tile 32x48 (acc[2][3]); B 3-deep reg prefetch (4 buffers); A dbuf.
// Per-block kb rotation + wave->Tg rotation to de-lockstep L2 B reads.
// ---------------------------------------------------------------------------
__global__ __launch_bounds__(256) void gemm32(
    const unsigned short* __restrict__ A, const unsigned short* __restrict__ Bpk,
    const float* __restrict__ bias, float* __restrict__ C, int ldc)
{
    __shared__ unsigned short Asl[2 * 24 * 64 * 8];   // 49,152 B
    const int tid = threadIdx.x, wave = tid >> 6, lane = tid & 63;
    const int m0 = blockIdx.x * 32;

    // stage A into swizzled fragment layout
#pragma unroll
    for (int uu = 0; uu < 12; ++uu) {
        const int s = tid + 256 * uu;                 // 0..3071
        const int mt = s / 1536;
        const int r2 = s - mt * 1536;
        const int kb = r2 >> 6;
        const int L  = r2 & 63;
        uintx4 v = *(const uintx4*)(A + (size_t)(m0 + mt * 16 + (L & 15)) * Hp
                                      + kb * 32 + (L >> 4) * 8);
        *(uintx4*)(&Asl[((mt * 24 + kb) * 64 + (L ^ (kb & 7))) * 8]) = v;
    }
    __syncthreads();

    const int mrow = lane & 15, kq = lane >> 4;
    const int rot = ((blockIdx.x * 5 + blockIdx.y) & 7) * 3;
    const int wavep = (wave + blockIdx.x) & 3;
    const int Tg0 = blockIdx.y * 12 + wavep * 3;
    const unsigned short* Bbase = Bpk + (size_t)Tg0 * 12288 + lane * 8;

    const floatx4 z = {0.f, 0.f, 0.f, 0.f};
    floatx4 acc[2][3];
#pragma unroll
    for (int mt = 0; mt < 2; ++mt)
#pragma unroll
        for (int nt = 0; nt < 3; ++nt) acc[mt][nt] = z;

    short8 bbuf[4][3], abuf[2][2];
#pragma unroll
    for (int d = 0; d < 3; ++d) {
        int kc = d + rot; if (kc >= 24) kc -= 24;
#pragma unroll
        for (int nt = 0; nt < 3; ++nt)
            bbuf[d][nt] = *(const short8*)(Bbase + (size_t)nt * 12288 + kc * 512);
    }
    {
        int kc = rot;
#pragma unroll
        for (int mt = 0; mt < 2; ++mt)
            abuf[0][mt] = *(const short8*)(&Asl[((mt * 24 + kc) * 64 + (lane ^ (kc & 7))) * 8]);
    }

#pragma unroll
    for (int kb = 0; kb < 24; ++kb) {
        if (kb + 3 < 24) {
            int kc = kb + 3 + rot; if (kc >= 24) kc -= 24;
#pragma unroll
            for (int nt = 0; nt < 3; ++nt)
                bbuf[(kb + 3) & 3][nt] =
                    *(const short8*)(Bbase + (size_t)nt * 12288 + kc * 512);
        }
        if (kb + 1 < 24) {
            int kc = kb + 1 + rot; if (kc >= 24) kc -= 24;
#pragma unroll
            for (int mt = 0; mt < 2; ++mt)
                abuf[(kb + 1) & 1][mt] = *(const short8*)(
                    &Asl[((mt * 24 + kc) * 64 + (lane ^ (kc & 7))) * 8]);
        }
        __builtin_amdgcn_s_setprio(1);
#pragma unroll
        for (int mt = 0; mt < 2; ++mt)
#pragma unroll
            for (int nt = 0; nt < 3; ++nt)
                acc[mt][nt] = __builtin_amdgcn_mfma_f32_16x16x32_bf16(
                    abuf[kb & 1][mt], bbuf[kb & 3][nt], acc[mt][nt], 0, 0, 0);
        __builtin_amdgcn_s_setprio(0);
    }

#pragma unroll
    for (int nt = 0; nt < 3; ++nt) {
        const int colg = (Tg0 + nt) * 16 + mrow;
        const float bv = bias ? bias[colg] : 0.0f;
#pragma unroll
        for (int mt = 0; mt < 2; ++mt)
#pragma unroll
            for (int r = 0; r < 4; ++r)
                C[(size_t)(m0 + mt * 16 + kq * 4 + r) * ldc + colg] = acc[mt][nt][r] + bv;
    }
}

// ---------------------------------------------------------------------------
// LN+ReLU -> enc fp32 (output) and enc bf16 (next GEMM A)
// enc_f is a final output (never re-read on device) -> non-temporal stores.
// ---------------------------------------------------------------------------
__global__ __launch_bounds__(256) void ln_relu(
    const float* __restrict__ pre, const float* __restrict__ g,
    const float* __restrict__ be, float* __restrict__ encf,
    unsigned short* __restrict__ encb)
{
    const int wave = threadIdx.x >> 6, lane = threadIdx.x & 63;
    const int row = blockIdx.x * 4 + wave;
    const float2* rp = (const float2*)(pre + (size_t)row * Hp);
    float2 x[6]; float s = 0.f, q = 0.f;
#pragma unroll
    for (int c = 0; c < 6; ++c) {
        x[c] = rp[lane + 64 * c];
        s += x[c].x + x[c].y;
        q += x[c].x * x[c].x + x[c].y * x[c].y;
    }
#pragma unroll
    for (int m = 1; m < 64; m <<= 1) { s += __shfl_xor(s, m, 64); q += __shfl_xor(q, m, 64); }
    const float mu = s * (1.0f / Hp);
    const float var = q * (1.0f / Hp) - mu * mu;
    const float rs = rsqrtf(var + EPS);
    floatx2* of = (floatx2*)(encf + (size_t)row * Hp);
    unsigned int* ob = (unsigned int*)(encb + (size_t)row * Hp);
#pragma unroll
    for (int c = 0; c < 6; ++c) {
        const float2 g2 = ((const float2*)g)[lane + 64 * c];
        const float2 b2 = ((const float2*)be)[lane + 64 * c];
        float y0 = fmaxf((x[c].x - mu) * rs * g2.x + b2.x, 0.f);
        float y1 = fmaxf((x[c].y - mu) * rs * g2.y + b2.y, 0.f);
        floatx2 y; y.x = y0; y.y = y1;
        __builtin_nontemporal_store(y, &of[lane + 64 * c]);
        ob[lane + 64 * c] = f2bf2(y0, y1);
    }
}

// ---------------------------------------------------------------------------
// graph_v2: block = (b, group of 6 i's). grid = 256 = 1 block/CU.
// All 48 hj rows staged fp32 in LDS (XOR-swizzled float4 rows); 6 hi rows +
// g/b/w2 in LDS. Each lane owns one (i=wave, j=lane) pair, k serial: no
// shuffles. Two passes over k via k-halving with 3 stagings.
// ---------------------------------------------------------------------------
__global__ __launch_bounds__(384) void graph_v2(
    const float* __restrict__ ws2, const float* __restrict__ gg_,
    const float* __restrict__ bb_, const float* __restrict__ Wg2,
    const float* __restrict__ bg2, float* __restrict__ out)
{
    __shared__ floatx4 HJ[96 * 64];        // 98,304 B (row-swizzled)
    __shared__ floatx4 HI[6 * 192];        // 18,432 B
    __shared__ floatx4 Gc[192];            // 3,072 B
    __shared__ floatx4 Bc[192];
    __shared__ floatx4 W2c[192];
    const int tid = threadIdx.x, wave = tid >> 6, lane = tid & 63;
    const int b = blockIdx.x >> 3, ig = blockIdx.x & 7;
    const floatx4* w4 = (const floatx4*)ws2;   // row stride 576 chunks

    // stage HI (6 rows) + LN params (once)
    for (int idx = tid; idx < 6 * 192; idx += 384) {
        const int i = idx / 192, c = idx - i * 192;
        HI[idx] = w4[(size_t)(b * 48 + ig * 6 + i) * 576 + c];
    }
    for (int c = tid; c < 192; c += 384) {
        Gc[c]  = ((const floatx4*)gg_)[c];
        Bc[c]  = ((const floatx4*)bb_)[c];
        W2c[c] = ((const floatx4*)Wg2)[c];
    }
    // stage HJ half 0 (k chunks 0..95)
    for (int idx = tid; idx < 48 * 96; idx += 384) {
        const int j = idx / 96, c = idx - j * 96;
        HJ[c * 64 + (j ^ (c & 7))] = w4[(size_t)(b * 48 + j) * 576 + 192 + c];
    }
    __syncthreads();

    float s = 0.f, q = 0.f, pd = 0.f, mu = 0.f, rs = 0.f;

    // pass A, half 0
    if (lane < 48) {
#pragma unroll 4
        for (int c = 0; c < 96; ++c) {
            const floatx4 x = HI[wave * 192 + c] + HJ[c * 64 + (lane ^ (c & 7))];
            s += x.x + x.y + x.z + x.w;
            q += x.x * x.x + x.y * x.y + x.z * x.z + x.w * x.w;
        }
    }
    __syncthreads();
    // stage HJ half 1 (k chunks 96..191)
    for (int idx = tid; idx < 48 * 96; idx += 384) {
        const int j = idx / 96, c = idx - j * 96;
        HJ[c * 64 + (j ^ (c & 7))] = w4[(size_t)(b * 48 + j) * 576 + 192 + 96 + c];
    }
    __syncthreads();

    // pass A half 1, then pass B half 1 (same data resident)
    if (lane < 48) {
#pragma unroll 4
        for (int c = 0; c < 96; ++c) {
            const floatx4 x = HI[wave * 192 + 96 + c] + HJ[c * 64 + (lane ^ (c & 7))];
            s += x.x + x.y + x.z + x.w;
            q += x.x * x.x + x.y * x.y + x.z * x.z + x.w * x.w;
        }
        mu = s * (1.0f / Hp);
        rs = rsqrtf(q * (1.0f / Hp) - mu * mu + EPS);
#pragma unroll 2
        for (int c = 0; c < 96; ++c) {
            const floatx4 x = HI[wave * 192 + 96 + c] + HJ[c * 64 + (lane ^ (c & 7))];
            const floatx4 g = Gc[96 + c], b2 = Bc[96 + c], w = W2c[96 + c];
            pd += fmaxf((x.x - mu) * rs * g.x + b2.x, 0.f) * w.x;
            pd += fmaxf((x.y - mu) * rs * g.y + b2.y, 0.f) * w.y;
            pd += fmaxf((x.z - mu) * rs * g.z + b2.z, 0.f) * w.z;
            pd += fmaxf((x.w - mu) * rs * g.w + b2.w, 0.f) * w.w;
        }
    }
    __syncthreads();
    // restage HJ half 0
    for (int idx = tid; idx < 48 * 96; idx += 384) {
        const int j = idx / 96, c = idx - j * 96;
        HJ[c * 64 + (j ^ (c & 7))] = w4[(size_t)(b * 48 + j) * 576 + 192 + c];
    }
    __syncthreads();

    // pass B half 0, then output
    if (lane < 48) {
#pragma unroll 2
        for (int c = 0; c < 96; ++c) {
            const floatx4 x = HI[wave * 192 + c] + HJ[c * 64 + (lane ^ (c & 7))];
            const floatx4 g = Gc[c], b2 = Bc[c], w = W2c[c];
            pd += fmaxf((x.x - mu) * rs * g.x + b2.x, 0.f) * w.x;
            pd += fmaxf((x.y - mu) * rs * g.y + b2.y, 0.f) * w.y;
            pd += fmaxf((x.z - mu) * rs * g.z + b2.z, 0.f) * w.z;
            pd += fmaxf((x.w - mu) * rs * g.w + b2.w, 0.f) * w.w;
        }
        const int ii = ig * 6 + wave;                 // global i, 0..47
        const float v = pd + bg2[0];
        const float sc = (ii == lane) ? 0.f : 1.f / (1.f + expf(-v));
        out[((size_t)b * 48 + ii) * 48 + lane] = sc;
    }
}

// ---------------------------------------------------------------------------
// effects96: block = 2 adjacent (b,i) pairs x half of N (384 cols).
// 512 threads, 144 KB LDS -> 1 block/CU, grid = 768 (3 balanced rounds).
// Phase 1 (T14 issue-early): ALL ws2 row loads hoisted ahead of the
// shuffle-reduce chains -> one latency exposure instead of three.
// Phase 2: acc[6][3], 3 global B + 6 LDS A per k-step, 3-deep B prefetch,
// setprio on MFMA bursts, NT stores.
// ---------------------------------------------------------------------------
__global__ __launch_bounds__(512, 2) void effects96(
    const float* __restrict__ ha, const float* __restrict__ ws2,
    const float* __restrict__ g_i, const float* __restrict__ b_i,
    const unsigned short* __restrict__ Bpk, const float* __restrict__ bi2,
    float* __restrict__ out)
{
    __shared__ unsigned short Asl[6 * 24 * 64 * 8];   // 147,456 B
    const int tid = threadIdx.x, wave = tid >> 6, lane = tid & 63;
    const int bid = blockIdx.x;          // 0..767
    const int pair = bid >> 1, nhalf = bid & 1;
    const int b = pair / 12;
    const int bi0 = b * Ip + (pair - b * 12) * 2;     // first of the two bi
    const int half = lane >> 5, hl = lane & 31;

    // ---- Phase 1: LN+ReLU for rows r = i_local*48 + j  (96 rows) ----
    {
        const floatx4* ha0 = (const floatx4*)(ha + (size_t)bi0 * Hp);
        const floatx4* ha1 = (const floatx4*)(ha + (size_t)(bi0 + 1) * Hp);
        const floatx4* gp = (const floatx4*)g_i;
        const floatx4* bp = (const floatx4*)b_i;
        floatx4 hv0[6], hv1[6], gv[6], bv[6];
#pragma unroll
        for (int t = 0; t < 3; ++t) {
            hv0[2*t] = ha0[2*hl + 64*t];  hv0[2*t+1] = ha0[2*hl + 1 + 64*t];
            hv1[2*t] = ha1[2*hl + 64*t];  hv1[2*t+1] = ha1[2*hl + 1 + 64*t];
            gv[2*t]  = gp[2*hl + 64*t];   gv[2*t+1]  = gp[2*hl + 1 + 64*t];
            bv[2*t]  = bp[2*hl + 64*t];   bv[2*t+1]  = bp[2*hl + 1 + 64*t];
        }

        // T14: issue all three j-row loads up front (compile-time indexed)
        floatx4 hb[3][6];
#pragma unroll
        for (int p = 0; p < 3; ++p) {
            const int j = wave * 6 + 2 * p + half;    // 0..47
            const floatx4* hbp = (const floatx4*)(ws2 + (size_t)(b * Vp + j) * 2304 + 1536);
#pragma unroll
            for (int t = 0; t < 3; ++t) {
                hb[p][2*t]   = hbp[2*hl + 64*t];
                hb[p][2*t+1] = hbp[2*hl + 1 + 64*t];
            }
        }

#pragma unroll
        for (int p = 0; p < 3; ++p) {
            const int j = wave * 6 + 2 * p + half;    // 0..47
            floatx4 x0[6], x1[6];
            float s0 = 0.f, q0 = 0.f, s1 = 0.f, q1 = 0.f;
#pragma unroll
            for (int c = 0; c < 6; ++c) {
                x0[c] = hv0[c] + hb[p][c];
                x1[c] = hv1[c] + hb[p][c];
            }
#pragma unroll
            for (int c = 0; c < 6; ++c) {
                s0 += x0[c].x + x0[c].y + x0[c].z + x0[c].w;
                q0 += x0[c].x*x0[c].x + x0[c].y*x0[c].y + x0[c].z*x0[c].z + x0[c].w*x0[c].w;
                s1 += x1[c].x + x1[c].y + x1[c].z + x1[c].w;
                q1 += x1[c].x*x1[c].x + x1[c].y*x1[c].y + x1[c].z*x1[c].z + x1[c].w*x1[c].w;
            }
#pragma unroll
            for (int m = 1; m < 32; m <<= 1) {
                s0 += __shfl_xor(s0, m, 64); q0 += __shfl_xor(q0, m, 64);
                s1 += __shfl_xor(s1, m, 64); q1 += __shfl_xor(q1, m, 64);
            }
            const float mu0 = s0 * (1.0f / Hp);
            const float rs0 = rsqrtf(q0 * (1.0f / Hp) - mu0 * mu0 + EPS);
            const float mu1 = s1 * (1.0f / Hp);
            const float rs1 = rsqrtf(q1 * (1.0f / Hp) - mu1 * mu1 + EPS);
            const int mt0 = j >> 4, mt1 = 3 + mt0, mr = j & 15;
#pragma unroll
            for (int t = 0; t < 3; ++t) {
                const int cpk = hl + 32 * t;          // chunk 0..95
                const int kb = cpk >> 2, kq2 = cpk & 3;
                const int swz = (kq2 * 16 + mr) ^ (kb & 7);
                uintx4 v0 = ln8(x0[2*t], x0[2*t+1], mu0, rs0,
                                gv[2*t], gv[2*t+1], bv[2*t], bv[2*t+1]);
                *(uintx4*)(&Asl[((mt0 * 24 + kb) * 64 + swz) * 8]) = v0;
                uintx4 v1 = ln8(x1[2*t], x1[2*t+1], mu1, rs1,
                                gv[2*t], gv[2*t+1], bv[2*t], bv[2*t+1]);
                *(uintx4*)(&Asl[((mt1 * 24 + kb) * 64 + swz) * 8]) = v1;
            }
        }
    }
    __syncthreads();

    // ---- Phase 2 ----
    const int mrow = lane & 15, kq = lane >> 4;
    const int rot = (pair & 7) * 3;
    const int wavep = (wave + pair) & 7;
    const int Tg0 = nhalf * 24 + wavep * 3;
    const unsigned short* Bbase = Bpk + (size_t)Tg0 * 12288 + lane * 8;

    const floatx4 z = {0.f, 0.f, 0.f, 0.f};
    floatx4 acc[6][3];
#pragma unroll
    for (int mt = 0; mt < 6; ++mt)
#pragma unroll
        for (int nt = 0; nt < 3; ++nt) acc[mt][nt] = z;

    short8 bbuf[4][3], abuf[2][6];
#pragma unroll
    for (int d = 0; d < 3; ++d) {
        int kc = d + rot; if (kc >= 24) kc -= 24;
#pragma unroll
        for (int nt = 0; nt < 3; ++nt)
            bbuf[d][nt] = *(const short8*)(Bbase + (size_t)nt * 12288 + kc * 512);
    }
    {
        int kc = rot;
#pragma unroll
        for (int mt = 0; mt < 6; ++mt)
            abuf[0][mt] = *(const short8*)(&Asl[((mt * 24 + kc) * 64 + (lane ^ (kc & 7))) * 8]);
    }

#pragma unroll
    for (int kb = 0; kb < 24; ++kb) {
        if (kb + 3 < 24) {
            int kc = kb + 3 + rot; if (kc >= 24) kc -= 24;
#pragma unroll
            for (int nt = 0; nt < 3; ++nt)
                bbuf[(kb + 3) & 3][nt] =
                    *(const short8*)(Bbase + (size_t)nt * 12288 + kc * 512);
        }
        if (kb + 1 < 24) {
            int kc = kb + 1 + rot; if (kc >= 24) kc -= 24;
#pragma unroll
            for (int mt = 0; mt < 6; ++mt)
                abuf[(kb + 1) & 1][mt] = *(const short8*)(
                    &Asl[((mt * 24 + kc) * 64 + (lane ^ (kc & 7))) * 8]);
        }
        __builtin_amdgcn_s_setprio(1);
#pragma unroll
        for (int mt = 0; mt < 6; ++mt)
#pragma unroll
            for (int nt = 0; nt < 3; ++nt)
                acc[mt][nt] = __builtin_amdgcn_mfma_f32_16x16x32_bf16(
                    abuf[kb & 1][mt], bbuf[kb & 3][nt], acc[mt][nt], 0, 0, 0);
        __builtin_amdgcn_s_setprio(0);
    }

    // rows for the pair are contiguous: global row = bi0*48 + rr, rr = 0..95
#pragma unroll
    for (int nt = 0; nt < 3; ++nt) {
        const int colg = (Tg0 + nt) * 16 + mrow;
        const float biasv = bi2[colg];
#pragma unroll
        for (int mt = 0; mt < 6; ++mt) {
#pragma unroll
            for (int r = 0; r < 4; ++r) {
                const int rr = mt * 16 + kq * 4 + r;
                __builtin_nontemporal_store(
                    acc[mt][nt][r] + biasv,
                    &out[(size_t)(bi0 * 48 + rr) * Hp + colg]);
            }
        }
    }
}

// ---------------------------------------------------------------------------
extern "C" void kernel_launch(void* const* d_in, const int* in_sizes, int n_in,
                              void* d_out, int out_size, void* d_ws, size_t ws_size,
                              hipStream_t stream) {
    const float* variables     = (const float*)d_in[0];
    const float* interventions = (const float*)d_in[1];
    const float* W_enc  = (const float*)d_in[2];
    const float* b_enc  = (const float*)d_in[3];
    const float* g_enc  = (const float*)d_in[4];
    const float* be_enc = (const float*)d_in[5];
    const float* Wg1 = (const float*)d_in[6];
    const float* bg1 = (const float*)d_in[7];
    const float* g_g = (const float*)d_in[8];
    const float* b_g = (const float*)d_in[9];
    const float* Wg2 = (const float*)d_in[10];
    const float* bg2 = (const float*)d_in[11];
    const float* Wi1 = (const float*)d_in[12];
    const float* bi1 = (const float*)d_in[13];
    const float* g_i = (const float*)d_in[14];
    const float* b_i = (const float*)d_in[15];
    const float* Wi2 = (const float*)d_in[16];
    const float* bi2 = (const float*)d_in[17];

    float* out = (float*)d_out;
    float* effects = out;
    float* graph = out + EFFECTS_SIZE;
    float* enc_f = out + EFFECTS_SIZE + GRAPH_SIZE;

    char* wsb = (char*)d_ws;
    unsigned short* packedW = (unsigned short*)wsb;                   // 7,077,888 B
    float* ws2  = (float*)(wsb + 7077888);                            // [1536][2304] fp32
    float* pre1 = ws2;                                                // alias (consumed first)
    float* ha   = (float*)(wsb + 7077888 + 14155776);                 // [768][768] fp32
    unsigned short* varb  = (unsigned short*)(wsb + 23592960);
    unsigned short* intvb = (unsigned short*)(wsb + 25952256);
    unsigned short* encb  = (unsigned short*)(wsb + 27131904);
    float* bias2304 = (float*)(wsb + 29491200);

    pack_weights<<<1728, 256, 0, stream>>>(W_enc, Wg1, Wi1, Wi2, packedW);
    convert_inputs<<<3456, 256, 0, stream>>>(variables, interventions, bg1, bi1,
                                             varb, intvb, bias2304);
    // pre1 = var @ W_enc + b_enc        [1536 x 768]
    gemm32<<<dim3(48, 4), 256, 0, stream>>>(varb, packedW, b_enc, pre1, Hp);
    // enc (fp32 to d_out, bf16 to ws)
    ln_relu<<<384, 256, 0, stream>>>(pre1, g_enc, be_enc, enc_f, encb);
    // ws2 = enc @ [Wg1a | Wg1b | Wi1b] + [0 | bg1 | bi1]   [1536 x 2304]
    gemm32<<<dim3(48, 12), 256, 0, stream>>>(encb, packedW + (size_t)1 * MS,
                                             bias2304, ws2, 2304);
    // ha = intv @ Wi1a                  [768 x 768]
    gemm32<<<dim3(24, 4), 256, 0, stream>>>(intvb, packedW + (size_t)4 * MS,
                                            nullptr, ha, Hp);
    graph_v2<<<256, 384, 0, stream>>>(ws2, g_g, b_g, Wg2, bg2, graph);
    effects96<<<768, 512, 0, stream>>>(ha, ws2, g_i, b_i,
                                       packedW + (size_t)5 * MS, bi2, effects);
}

// Round 5
// 280.688 us; speedup vs baseline: 1.0858x; 1.0858x over previous
//
#include <hip/hip_runtime.h>
#include <math.h>

#define Bp 32
#define Vp 48
#define Ip 24
#define Hp 768
#define EPS 1e-5f

#define EFFECTS_SIZE (Bp*Ip*Vp*Hp)   // 28,311,552
#define GRAPH_SIZE   (Bp*Vp*Vp)      // 73,728
#define ENC_SIZE     (Bp*Vp*Hp)      // 1,179,648
#define MS           (Hp*Hp)         // packed matrix size in ushorts

typedef __attribute__((ext_vector_type(8))) short short8;
typedef __attribute__((ext_vector_type(4))) float floatx4;
typedef __attribute__((ext_vector_type(2))) float floatx2;
typedef __attribute__((ext_vector_type(2))) unsigned int uintx2;
typedef __attribute__((ext_vector_type(4))) unsigned int uintx4;

__device__ __forceinline__ unsigned short f2bf(float f) {
    unsigned int u = __float_as_uint(f);
    u += 0x7fffu + ((u >> 16) & 1u);
    return (unsigned short)(u >> 16);
}
__device__ __forceinline__ unsigned int f2bf2(float a, float b) {
    return (unsigned int)f2bf(a) | ((unsigned int)f2bf(b) << 16);
}

// LN+ReLU 8 consecutive elements (two floatx4) -> packed bf16x8
__device__ __forceinline__ uintx4 ln8(floatx4 xa, floatx4 xb, float mu, float rs,
                                      floatx4 ga, floatx4 gb, floatx4 ba, floatx4 bb)
{
    float y0 = fmaxf((xa.x - mu) * rs * ga.x + ba.x, 0.f);
    float y1 = fmaxf((xa.y - mu) * rs * ga.y + ba.y, 0.f);
    float y2 = fmaxf((xa.z - mu) * rs * ga.z + ba.z, 0.f);
    float y3 = fmaxf((xa.w - mu) * rs * ga.w + ba.w, 0.f);
    float y4 = fmaxf((xb.x - mu) * rs * gb.x + bb.x, 0.f);
    float y5 = fmaxf((xb.y - mu) * rs * gb.y + bb.y, 0.f);
    float y6 = fmaxf((xb.z - mu) * rs * gb.z + bb.z, 0.f);
    float y7 = fmaxf((xb.w - mu) * rs * gb.w + bb.w, 0.f);
    uintx4 v;
    v.x = f2bf2(y0, y1); v.y = f2bf2(y2, y3);
    v.z = f2bf2(y4, y5); v.w = f2bf2(y6, y7);
    return v;
}

// ---------------------------------------------------------------------------
// Pack 6 H x H weight blocks into MFMA B-operand layout (bf16).
// packed[m][((T*24+kb)*64+lane)*8 + j] = W[kb*32+(lane>>4)*8+j][T*16+(lane&15)]
// slots: 0=W_enc 1=Wg1a 2=Wg1b 3=Wi1b 4=Wi1a 5=Wi2
// ---------------------------------------------------------------------------
__global__ __launch_bounds__(256) void pack_weights(
    const float* __restrict__ W_enc, const float* __restrict__ Wg1,
    const float* __restrict__ Wi1, const float* __restrict__ Wi2,
    unsigned short* __restrict__ packed)
{
    const int bid = blockIdx.x;          // 0..1727
    const int m = bid / 288;
    const int rem = bid - m * 288;
    const int T = rem / 6;
    const int u = rem - T * 6;
    const float* src;
    switch (m) {
        case 0: src = W_enc; break;
        case 1: src = Wg1; break;
        case 2: src = Wg1 + Hp * Hp; break;
        case 3: src = Wi1 + Hp * Hp; break;
        case 4: src = Wi1; break;
        default: src = Wi2; break;
    }
    unsigned short* dst = packed + (size_t)m * MS;
    const int lane = threadIdx.x & 63;
    const int kq = threadIdx.x >> 6;     // 0..3
    const int col = T * 16 + (lane & 15);
    const int krow0 = (lane >> 4) * 8;
    const int kb = kq + 4 * u;           // 0..23
    unsigned int w[4];
#pragma unroll
    for (int p2 = 0; p2 < 4; ++p2) {
        float f0 = src[(size_t)(kb * 32 + krow0 + 2 * p2)     * Hp + col];
        float f1 = src[(size_t)(kb * 32 + krow0 + 2 * p2 + 1) * Hp + col];
        w[p2] = f2bf2(f0, f1);
    }
    uintx4 v; v.x = w[0]; v.y = w[1]; v.z = w[2]; v.w = w[3];
    *(uintx4*)(dst + ((size_t)(T * 24 + kb) * 64 + lane) * 8) = v;
}

// ---------------------------------------------------------------------------
// Convert variables+interventions fp32 -> bf16; block 0 also builds bias2304.
// ---------------------------------------------------------------------------
__global__ __launch_bounds__(256) void convert_inputs(
    const float* __restrict__ vars, const float* __restrict__ intv,
    const float* __restrict__ bg1, const float* __restrict__ bi1,
    unsigned short* __restrict__ varb, unsigned short* __restrict__ intvb,
    float* __restrict__ bias2304)
{
    const int p = blockIdx.x * 256 + threadIdx.x;
    const int VPn = ENC_SIZE / 2;
    if (p < VPn) {
        float2 f = ((const float2*)vars)[p];
        ((unsigned int*)varb)[p] = f2bf2(f.x, f.y);
    } else {
        int q = p - VPn;
        float2 f = ((const float2*)intv)[q];
        ((unsigned int*)intvb)[q] = f2bf2(f.x, f.y);
    }
    if (blockIdx.x == 0) {
        for (int t = threadIdx.x; t < 2304; t += 256)
            bias2304[t] = (t < 768) ? 0.0f : (t < 1536 ? bg1[t - 768] : bi1[t - 1536]);
    }
}

// ---------------------------------------------------------------------------
// gemm32: C[M x N] = A_bf16[M x 768] @ Bpacked (+bias).
// Block = 32 rows x 192 cols (grid.x = M/32, grid.y = N/192). 48 KB LDS.
// Wave tile 32x48 (acc[2][3]); B 3-deep reg prefetch (4 buffers); A dbuf.
// Per-block kb rotation + wave->Tg rotation to de-lockstep L2 B reads.
// ---------------------------------------------------------------------------
__global__ __launch_bounds__(256) void gemm32(
    const unsigned short* __restrict__ A, const unsigned short* __restrict__ Bpk,
    const float* __restrict__ bias, float* __restrict__ C, int ldc)
{
    __shared__ unsigned short Asl[2 * 24 * 64 * 8];   // 49,152 B
    const int tid = threadIdx.x, wave = tid >> 6, lane = tid & 63;
    const int m0 = blockIdx.x * 32;

    // stage A into swizzled fragment layout
#pragma unroll
    for (int uu = 0; uu < 12; ++uu) {
        const int s = tid + 256 * uu;                 // 0..3071
        const int mt = s / 1536;
        const int r2 = s - mt * 1536;
        const int kb = r2 >> 6;
        const int L  = r2 & 63;
        uintx4 v = *(const uintx4*)(A + (size_t)(m0 + mt * 16 + (L & 15)) * Hp
                                      + kb * 32 + (L >> 4) * 8);
        *(uintx4*)(&Asl[((mt * 24 + kb) * 64 + (L ^ (kb & 7))) * 8]) = v;
    }
    __syncthreads();

    const int mrow = lane & 15, kq = lane >> 4;
    const int rot = ((blockIdx.x * 5 + blockIdx.y) & 7) * 3;
    const int wavep = (wave + blockIdx.x) & 3;
    const int Tg0 = blockIdx.y * 12 + wavep * 3;
    const unsigned short* Bbase = Bpk + (size_t)Tg0 * 12288 + lane * 8;

    const floatx4 z = {0.f, 0.f, 0.f, 0.f};
    floatx4 acc[2][3];
#pragma unroll
    for (int mt = 0; mt < 2; ++mt)
#pragma unroll
        for (int nt = 0; nt < 3; ++nt) acc[mt][nt] = z;

    short8 bbuf[4][3], abuf[2][2];
#pragma unroll
    for (int d = 0; d < 3; ++d) {
        int kc = d + rot; if (kc >= 24) kc -= 24;
#pragma unroll
        for (int nt = 0; nt < 3; ++nt)
            bbuf[d][nt] = *(const short8*)(Bbase + (size_t)nt * 12288 + kc * 512);
    }
    {
        int kc = rot;
#pragma unroll
        for (int mt = 0; mt < 2; ++mt)
            abuf[0][mt] = *(const short8*)(&Asl[((mt * 24 + kc) * 64 + (lane ^ (kc & 7))) * 8]);
    }

#pragma unroll
    for (int kb = 0; kb < 24; ++kb) {
        if (kb + 3 < 24) {
            int kc = kb + 3 + rot; if (kc >= 24) kc -= 24;
#pragma unroll
            for (int nt = 0; nt < 3; ++nt)
                bbuf[(kb + 3) & 3][nt] =
                    *(const short8*)(Bbase + (size_t)nt * 12288 + kc * 512);
        }
        if (kb + 1 < 24) {
            int kc = kb + 1 + rot; if (kc >= 24) kc -= 24;
#pragma unroll
            for (int mt = 0; mt < 2; ++mt)
                abuf[(kb + 1) & 1][mt] = *(const short8*)(
                    &Asl[((mt * 24 + kc) * 64 + (lane ^ (kc & 7))) * 8]);
        }
        __builtin_amdgcn_s_setprio(1);
#pragma unroll
        for (int mt = 0; mt < 2; ++mt)
#pragma unroll
            for (int nt = 0; nt < 3; ++nt)
                acc[mt][nt] = __builtin_amdgcn_mfma_f32_16x16x32_bf16(
                    abuf[kb & 1][mt], bbuf[kb & 3][nt], acc[mt][nt], 0, 0, 0);
        __builtin_amdgcn_s_setprio(0);
    }

#pragma unroll
    for (int nt = 0; nt < 3; ++nt) {
        const int colg = (Tg0 + nt) * 16 + mrow;
        const float bv = bias ? bias[colg] : 0.0f;
#pragma unroll
        for (int mt = 0; mt < 2; ++mt)
#pragma unroll
            for (int r = 0; r < 4; ++r)
                C[(size_t)(m0 + mt * 16 + kq * 4 + r) * ldc + colg] = acc[mt][nt][r] + bv;
    }
}

// ---------------------------------------------------------------------------
// gemm_ln: fused variable_encoder = LN(ReLU path): block = 16 rows x ALL 768
// cols. GEMM result staged fp32 in LDS, then LN+ReLU epilogue -> enc fp32
// (NT, final output) + enc bf16 (next GEMM A). Replaces gemm32-pre1 +
// ln_relu: one less launch, 19 MB less global round-trip, one less serial
// latency exposure in the dependency chain. Grid = 96 blocks.
// ---------------------------------------------------------------------------
__global__ __launch_bounds__(256) void gemm_ln(
    const unsigned short* __restrict__ A, const unsigned short* __restrict__ Bpk,
    const float* __restrict__ bias, const float* __restrict__ g,
    const float* __restrict__ be, float* __restrict__ encf,
    unsigned short* __restrict__ encb)
{
    __shared__ unsigned short Asl[24 * 64 * 8];   // 24,576 B (16 rows x 768 k)
    __shared__ float Cl[16 * 772];                // 49,408 B (stride 772 anti-conflict)
    const int tid = threadIdx.x, wave = tid >> 6, lane = tid & 63;
    const int m0 = blockIdx.x * 16;

    // stage A (16 rows) into swizzled fragment layout
#pragma unroll
    for (int uu = 0; uu < 6; ++uu) {
        const int s = tid + 256 * uu;             // 0..1535
        const int kb = s >> 6, L = s & 63;
        uintx4 v = *(const uintx4*)(A + (size_t)(m0 + (L & 15)) * Hp
                                      + kb * 32 + (L >> 4) * 8);
        *(uintx4*)(&Asl[(kb * 64 + (L ^ (kb & 7))) * 8]) = v;
    }
    __syncthreads();

    const int mrow = lane & 15, kq = lane >> 4;
    const floatx4 z = {0.f, 0.f, 0.f, 0.f};
#pragma unroll
    for (int G = 0; G < 2; ++G) {
        const int Tg0 = G * 24 + wave * 6;        // 6 Tg groups = 96 cols / wave / pass
        const unsigned short* Bbase = Bpk + (size_t)Tg0 * 12288 + lane * 8;
        floatx4 acc[6];
#pragma unroll
        for (int nt = 0; nt < 6; ++nt) acc[nt] = z;
        short8 bbuf[4][6], abuf[2];
#pragma unroll
        for (int d = 0; d < 3; ++d)
#pragma unroll
            for (int nt = 0; nt < 6; ++nt)
                bbuf[d][nt] = *(const short8*)(Bbase + (size_t)nt * 12288 + d * 512);
        abuf[0] = *(const short8*)(&Asl[(0 * 64 + (lane ^ 0)) * 8]);

#pragma unroll
        for (int kb = 0; kb < 24; ++kb) {
            if (kb + 3 < 24) {
                const int kc = kb + 3;
#pragma unroll
                for (int nt = 0; nt < 6; ++nt)
                    bbuf[(kb + 3) & 3][nt] =
                        *(const short8*)(Bbase + (size_t)nt * 12288 + kc * 512);
            }
            if (kb + 1 < 24) {
                const int kc = kb + 1;
                abuf[(kb + 1) & 1] = *(const short8*)(
                    &Asl[(kc * 64 + (lane ^ (kc & 7))) * 8]);
            }
            __builtin_amdgcn_s_setprio(1);
#pragma unroll
            for (int nt = 0; nt < 6; ++nt)
                acc[nt] = __builtin_amdgcn_mfma_f32_16x16x32_bf16(
                    abuf[kb & 1], bbuf[kb & 3][nt], acc[nt], 0, 0, 0);
            __builtin_amdgcn_s_setprio(0);
        }

#pragma unroll
        for (int nt = 0; nt < 6; ++nt) {
            const int colg = (Tg0 + nt) * 16 + mrow;
            const float bv = bias[colg];
#pragma unroll
            for (int r = 0; r < 4; ++r)
                Cl[(kq * 4 + r) * 772 + colg] = acc[nt][r] + bv;
        }
    }
    __syncthreads();

    // LN + ReLU epilogue: wave handles 4 rows
    floatx4 gv[3], bev[3];
#pragma unroll
    for (int t = 0; t < 3; ++t) {
        gv[t]  = ((const floatx4*)g)[lane + 64 * t];
        bev[t] = ((const floatx4*)be)[lane + 64 * t];
    }
#pragma unroll
    for (int rr = 0; rr < 4; ++rr) {
        const int row = wave * 4 + rr;
        const floatx4* cp = (const floatx4*)(Cl + row * 772);
        floatx4 x[3]; float s = 0.f, q = 0.f;
#pragma unroll
        for (int t = 0; t < 3; ++t) {
            x[t] = cp[lane + 64 * t];
            s += x[t].x + x[t].y + x[t].z + x[t].w;
            q += x[t].x*x[t].x + x[t].y*x[t].y + x[t].z*x[t].z + x[t].w*x[t].w;
        }
#pragma unroll
        for (int m = 1; m < 64; m <<= 1) { s += __shfl_xor(s, m, 64); q += __shfl_xor(q, m, 64); }
        const float mu = s * (1.0f / Hp);
        const float rs = rsqrtf(q * (1.0f / Hp) - mu * mu + EPS);
        floatx4* of = (floatx4*)(encf + (size_t)(m0 + row) * Hp);
        uintx2* ob = (uintx2*)(encb + (size_t)(m0 + row) * Hp);
#pragma unroll
        for (int t = 0; t < 3; ++t) {
            floatx4 y;
            y.x = fmaxf((x[t].x - mu) * rs * gv[t].x + bev[t].x, 0.f);
            y.y = fmaxf((x[t].y - mu) * rs * gv[t].y + bev[t].y, 0.f);
            y.z = fmaxf((x[t].z - mu) * rs * gv[t].z + bev[t].z, 0.f);
            y.w = fmaxf((x[t].w - mu) * rs * gv[t].w + bev[t].w, 0.f);
            __builtin_nontemporal_store(y, &of[lane + 64 * t]);
            uintx2 p; p.x = f2bf2(y.x, y.y); p.y = f2bf2(y.z, y.w);
            ob[lane + 64 * t] = p;
        }
    }
}

// ---------------------------------------------------------------------------
// Causal graph: block = (b,i); each wave handles 12 j's, unrolled by 2.
// float4 loads (4x fewer L2 requests) + 4 independent reduction chains.
// ---------------------------------------------------------------------------
__global__ __launch_bounds__(256) void graph_kernel(
    const float* __restrict__ ws2, const float* __restrict__ gg_,
    const float* __restrict__ bb_, const float* __restrict__ Wg2,
    const float* __restrict__ bg2, float* __restrict__ out)
{
    const int wave = threadIdx.x >> 6, lane = threadIdx.x & 63;
    const int p = blockIdx.x;
    const int b = p / Vp, i = p - b * Vp;
    const floatx4* hi4 = (const floatx4*)(ws2 + (size_t)p * 2304);
    const floatx4* gg4 = (const floatx4*)gg_;
    const floatx4* bb4 = (const floatx4*)bb_;
    const floatx4* w24 = (const floatx4*)Wg2;
    floatx4 ri[3], gg[3], bb[3], w2[3];
#pragma unroll
    for (int c = 0; c < 3; ++c) {
        const int k = lane + 64 * c;
        ri[c] = hi4[k]; gg[c] = gg4[k]; bb[c] = bb4[k]; w2[c] = w24[k];
    }
    const float bg2v = bg2[0];
    const int j0 = wave * 12;
    for (int jj = 0; jj < 12; jj += 2) {
        const int jA = j0 + jj, jB = jA + 1;
        const floatx4* hjA = (const floatx4*)(ws2 + (size_t)(b * Vp + jA) * 2304 + 768);
        const floatx4* hjB = (const floatx4*)(ws2 + (size_t)(b * Vp + jB) * 2304 + 768);
        floatx4 xA[3], xB[3];
        float sA = 0.f, qA = 0.f, sB = 0.f, qB = 0.f;
#pragma unroll
        for (int c = 0; c < 3; ++c) {
            const int k = lane + 64 * c;
            xA[c] = ri[c] + hjA[k];
            xB[c] = ri[c] + hjB[k];
            sA += xA[c].x + xA[c].y + xA[c].z + xA[c].w;
            qA += xA[c].x * xA[c].x + xA[c].y * xA[c].y + xA[c].z * xA[c].z + xA[c].w * xA[c].w;
            sB += xB[c].x + xB[c].y + xB[c].z + xB[c].w;
            qB += xB[c].x * xB[c].x + xB[c].y * xB[c].y + xB[c].z * xB[c].z + xB[c].w * xB[c].w;
        }
#pragma unroll
        for (int m = 1; m < 64; m <<= 1) {
            sA += __shfl_xor(sA, m, 64); qA += __shfl_xor(qA, m, 64);
            sB += __shfl_xor(sB, m, 64); qB += __shfl_xor(qB, m, 64);
        }
        const float muA = sA * (1.0f / Hp);
        const float rsA = rsqrtf(qA * (1.0f / Hp) - muA * muA + EPS);
        const float muB = sB * (1.0f / Hp);
        const float rsB = rsqrtf(qB * (1.0f / Hp) - muB * muB + EPS);
        float pdA = 0.f, pdB = 0.f;
#pragma unroll
        for (int c = 0; c < 3; ++c) {
            float yA0 = fmaxf((xA[c].x - muA) * rsA * gg[c].x + bb[c].x, 0.f);
            float yA1 = fmaxf((xA[c].y - muA) * rsA * gg[c].y + bb[c].y, 0.f);
            float yA2 = fmaxf((xA[c].z - muA) * rsA * gg[c].z + bb[c].z, 0.f);
            float yA3 = fmaxf((xA[c].w - muA) * rsA * gg[c].w + bb[c].w, 0.f);
            pdA = fmaf(yA0, w2[c].x, pdA); pdA = fmaf(yA1, w2[c].y, pdA);
            pdA = fmaf(yA2, w2[c].z, pdA); pdA = fmaf(yA3, w2[c].w, pdA);
            float yB0 = fmaxf((xB[c].x - muB) * rsB * gg[c].x + bb[c].x, 0.f);
            float yB1 = fmaxf((xB[c].y - muB) * rsB * gg[c].y + bb[c].y, 0.f);
            float yB2 = fmaxf((xB[c].z - muB) * rsB * gg[c].z + bb[c].z, 0.f);
            float yB3 = fmaxf((xB[c].w - muB) * rsB * gg[c].w + bb[c].w, 0.f);
            pdB = fmaf(yB0, w2[c].x, pdB); pdB = fmaf(yB1, w2[c].y, pdB);
            pdB = fmaf(yB2, w2[c].z, pdB); pdB = fmaf(yB3, w2[c].w, pdB);
        }
#pragma unroll
        for (int m = 1; m < 64; m <<= 1) {
            pdA += __shfl_xor(pdA, m, 64);
            pdB += __shfl_xor(pdB, m, 64);
        }
        if (lane == 0) {
            float scA = (i == jA) ? 0.0f : 1.0f / (1.0f + expf(-(pdA + bg2v)));
            float scB = (i == jB) ? 0.0f : 1.0f / (1.0f + expf(-(pdB + bg2v)));
            out[(size_t)p * Vp + jA] = scA;
            out[(size_t)p * Vp + jB] = scB;
        }
    }
}

// ---------------------------------------------------------------------------
// effects96: block = 2 adjacent (b,i) pairs x half of N (384 cols).
// 512 threads, 144 KB LDS, grid = 768 (balanced: 3 rounds at 1 block/CU).
// (round-2 verbatim: the best-measured version, 72.7 us)
// ---------------------------------------------------------------------------
__global__ __launch_bounds__(512, 2) void effects96(
    const float* __restrict__ ha, const float* __restrict__ ws2,
    const float* __restrict__ g_i, const float* __restrict__ b_i,
    const unsigned short* __restrict__ Bpk, const float* __restrict__ bi2,
    float* __restrict__ out)
{
    __shared__ unsigned short Asl[6 * 24 * 64 * 8];   // 147,456 B
    const int tid = threadIdx.x, wave = tid >> 6, lane = tid & 63;
    const int bid = blockIdx.x;          // 0..767
    const int pair = bid >> 1, nhalf = bid & 1;
    const int b = pair / 12;
    const int bi0 = b * Ip + (pair - b * 12) * 2;     // first of the two bi
    const int half = lane >> 5, hl = lane & 31;

    // ---- Phase 1: LN+ReLU for rows r = i_local*48 + j  (96 rows) ----
    {
        const floatx4* ha0 = (const floatx4*)(ha + (size_t)bi0 * Hp);
        const floatx4* ha1 = (const floatx4*)(ha + (size_t)(bi0 + 1) * Hp);
        const floatx4* gp = (const floatx4*)g_i;
        const floatx4* bp = (const floatx4*)b_i;
        floatx4 hv0[6], hv1[6], gv[6], bv[6];
#pragma unroll
        for (int t = 0; t < 3; ++t) {
            hv0[2*t] = ha0[2*hl + 64*t];  hv0[2*t+1] = ha0[2*hl + 1 + 64*t];
            hv1[2*t] = ha1[2*hl + 64*t];  hv1[2*t+1] = ha1[2*hl + 1 + 64*t];
            gv[2*t]  = gp[2*hl + 64*t];   gv[2*t+1]  = gp[2*hl + 1 + 64*t];
            bv[2*t]  = bp[2*hl + 64*t];   bv[2*t+1]  = bp[2*hl + 1 + 64*t];
        }

#pragma unroll
        for (int p = 0; p < 3; ++p) {
            const int j = wave * 6 + 2 * p + half;    // 0..47
            const floatx4* hbp = (const floatx4*)(ws2 + (size_t)(b * Vp + j) * 2304 + 1536);
            floatx4 x0[6], x1[6];
            float s0 = 0.f, q0 = 0.f, s1 = 0.f, q1 = 0.f;
#pragma unroll
            for (int t = 0; t < 3; ++t) {
                const floatx4 hA = hbp[2*hl + 64*t];
                const floatx4 hB = hbp[2*hl + 1 + 64*t];
                x0[2*t]   = hv0[2*t]   + hA;  x0[2*t+1] = hv0[2*t+1] + hB;
                x1[2*t]   = hv1[2*t]   + hA;  x1[2*t+1] = hv1[2*t+1] + hB;
            }
#pragma unroll
            for (int c = 0; c < 6; ++c) {
                s0 += x0[c].x + x0[c].y + x0[c].z + x0[c].w;
                q0 += x0[c].x*x0[c].x + x0[c].y*x0[c].y + x0[c].z*x0[c].z + x0[c].w*x0[c].w;
                s1 += x1[c].x + x1[c].y + x1[c].z + x1[c].w;
                q1 += x1[c].x*x1[c].x + x1[c].y*x1[c].y + x1[c].z*x1[c].z + x1[c].w*x1[c].w;
            }
#pragma unroll
            for (int m = 1; m < 32; m <<= 1) {
                s0 += __shfl_xor(s0, m, 64); q0 += __shfl_xor(q0, m, 64);
                s1 += __shfl_xor(s1, m, 64); q1 += __shfl_xor(q1, m, 64);
            }
            const float mu0 = s0 * (1.0f / Hp);
            const float rs0 = rsqrtf(q0 * (1.0f / Hp) - mu0 * mu0 + EPS);
            const float mu1 = s1 * (1.0f / Hp);
            const float rs1 = rsqrtf(q1 * (1.0f / Hp) - mu1 * mu1 + EPS);
            const int mt0 = j >> 4, mt1 = 3 + mt0, mr = j & 15;
#pragma unroll
            for (int t = 0; t < 3; ++t) {
                const int cpk = hl + 32 * t;          // chunk 0..95
                const int kb = cpk >> 2, kq2 = cpk & 3;
                const int swz = (kq2 * 16 + mr) ^ (kb & 7);
                uintx4 v0 = ln8(x0[2*t], x0[2*t+1], mu0, rs0,
                                gv[2*t], gv[2*t+1], bv[2*t], bv[2*t+1]);
                *(uintx4*)(&Asl[((mt0 * 24 + kb) * 64 + swz) * 8]) = v0;
                uintx4 v1 = ln8(x1[2*t], x1[2*t+1], mu1, rs1,
                                gv[2*t], gv[2*t+1], bv[2*t], bv[2*t+1]);
                *(uintx4*)(&Asl[((mt1 * 24 + kb) * 64 + swz) * 8]) = v1;
            }
        }
    }
    __syncthreads();

    // ---- Phase 2 ----
    const int mrow = lane & 15, kq = lane >> 4;
    const int rot = (pair & 7) * 3;
    const int wavep = (wave + pair) & 7;
    const int Tg0 = nhalf * 24 + wavep * 3;
    const unsigned short* Bbase = Bpk + (size_t)Tg0 * 12288 + lane * 8;

    const floatx4 z = {0.f, 0.f, 0.f, 0.f};
    floatx4 acc[6][3];
#pragma unroll
    for (int mt = 0; mt < 6; ++mt)
#pragma unroll
        for (int nt = 0; nt < 3; ++nt) acc[mt][nt] = z;

    short8 bbuf[4][3], abuf[2][6];
#pragma unroll
    for (int d = 0; d < 3; ++d) {
        int kc = d + rot; if (kc >= 24) kc -= 24;
#pragma unroll
        for (int nt = 0; nt < 3; ++nt)
            bbuf[d][nt] = *(const short8*)(Bbase + (size_t)nt * 12288 + kc * 512);
    }
    {
        int kc = rot;
#pragma unroll
        for (int mt = 0; mt < 6; ++mt)
            abuf[0][mt] = *(const short8*)(&Asl[((mt * 24 + kc) * 64 + (lane ^ (kc & 7))) * 8]);
    }

#pragma unroll
    for (int kb = 0; kb < 24; ++kb) {
        if (kb + 3 < 24) {
            int kc = kb + 3 + rot; if (kc >= 24) kc -= 24;
#pragma unroll
            for (int nt = 0; nt < 3; ++nt)
                bbuf[(kb + 3) & 3][nt] =
                    *(const short8*)(Bbase + (size_t)nt * 12288 + kc * 512);
        }
        if (kb + 1 < 24) {
            int kc = kb + 1 + rot; if (kc >= 24) kc -= 24;
#pragma unroll
            for (int mt = 0; mt < 6; ++mt)
                abuf[(kb + 1) & 1][mt] = *(const short8*)(
                    &Asl[((mt * 24 + kc) * 64 + (lane ^ (kc & 7))) * 8]);
        }
        __builtin_amdgcn_s_setprio(1);
#pragma unroll
        for (int mt = 0; mt < 6; ++mt)
#pragma unroll
            for (int nt = 0; nt < 3; ++nt)
                acc[mt][nt] = __builtin_amdgcn_mfma_f32_16x16x32_bf16(
                    abuf[kb & 1][mt], bbuf[kb & 3][nt], acc[mt][nt], 0, 0, 0);
        __builtin_amdgcn_s_setprio(0);
    }

    // rows for the pair are contiguous: global row = bi0*48 + rr, rr = 0..95
#pragma unroll
    for (int nt = 0; nt < 3; ++nt) {
        const int colg = (Tg0 + nt) * 16 + mrow;
        const float biasv = bi2[colg];
#pragma unroll
        for (int mt = 0; mt < 6; ++mt) {
#pragma unroll
            for (int r = 0; r < 4; ++r) {
                const int rr = mt * 16 + kq * 4 + r;
                __builtin_nontemporal_store(
                    acc[mt][nt][r] + biasv,
                    &out[(size_t)(bi0 * 48 + rr) * Hp + colg]);
            }
        }
    }
}

// ---------------------------------------------------------------------------
extern "C" void kernel_launch(void* const* d_in, const int* in_sizes, int n_in,
                              void* d_out, int out_size, void* d_ws, size_t ws_size,
                              hipStream_t stream) {
    const float* variables     = (const float*)d_in[0];
    const float* interventions = (const float*)d_in[1];
    const float* W_enc  = (const float*)d_in[2];
    const float* b_enc  = (const float*)d_in[3];
    const float* g_enc  = (const float*)d_in[4];
    const float* be_enc = (const float*)d_in[5];
    const float* Wg1 = (const float*)d_in[6];
    const float* bg1 = (const float*)d_in[7];
    const float* g_g = (const float*)d_in[8];
    const float* b_g = (const float*)d_in[9];
    const float* Wg2 = (const float*)d_in[10];
    const float* bg2 = (const float*)d_in[11];
    const float* Wi1 = (const float*)d_in[12];
    const float* bi1 = (const float*)d_in[13];
    const float* g_i = (const float*)d_in[14];
    const float* b_i = (const float*)d_in[15];
    const float* Wi2 = (const float*)d_in[16];
    const float* bi2 = (const float*)d_in[17];

    float* out = (float*)d_out;
    float* effects = out;
    float* graph = out + EFFECTS_SIZE;
    float* enc_f = out + EFFECTS_SIZE + GRAPH_SIZE;

    char* wsb = (char*)d_ws;
    unsigned short* packedW = (unsigned short*)wsb;                   // 7,077,888 B
    float* ws2  = (float*)(wsb + 7077888);                            // [1536][2304] fp32
    float* ha   = (float*)(wsb + 7077888 + 14155776);                 // [768][768] fp32
    unsigned short* varb  = (unsigned short*)(wsb + 23592960);
    unsigned short* intvb = (unsigned short*)(wsb + 25952256);
    unsigned short* encb  = (unsigned short*)(wsb + 27131904);
    float* bias2304 = (float*)(wsb + 29491200);

    pack_weights<<<1728, 256, 0, stream>>>(W_enc, Wg1, Wi1, Wi2, packedW);
    convert_inputs<<<3456, 256, 0, stream>>>(variables, interventions, bg1, bi1,
                                             varb, intvb, bias2304);
    // enc = relu(ln(var @ W_enc + b_enc)) : fp32 to d_out, bf16 to ws (fused)
    gemm_ln<<<96, 256, 0, stream>>>(varb, packedW, b_enc, g_enc, be_enc,
                                    enc_f, encb);
    // ws2 = enc @ [Wg1a | Wg1b | Wi1b] + [0 | bg1 | bi1]   [1536 x 2304]
    gemm32<<<dim3(48, 12), 256, 0, stream>>>(encb, packedW + (size_t)1 * MS,
                                             bias2304, ws2, 2304);
    // ha = intv @ Wi1a                  [768 x 768]
    gemm32<<<dim3(24, 4), 256, 0, stream>>>(intvb, packedW + (size_t)4 * MS,
                                            nullptr, ha, Hp);
    graph_kernel<<<Bp * Vp, 256, 0, stream>>>(ws2, g_g, b_g, Wg2, bg2, graph);
    effects96<<<768, 512, 0, stream>>>(ha, ws2, g_i, b_i,
                                       packedW + (size_t)5 * MS, bi2, effects);
}